// Round 7
// baseline (202.681 us; speedup 1.0000x reference)
//
#include <hip/hip_runtime.h>

// Native clang vector type — required by __builtin_nontemporal_{load,store}
// (HIP_vector_type float4 is rejected). Supports elementwise +=.
typedef float f32x4 __attribute__((ext_vector_type(4)));

// Problem constants (from reference):
constexpr int kB  = 256;    // batch
constexpr int kN  = 1000;   // classes
constexpr int kA  = 32;     // attention parts
constexpr int kC  = 512;    // channels
constexpr int kAC = kA * kC;            // 16384 floats per (class or sample)
constexpr int kFeat  = kB * kAC;        // 4,194,304
constexpr int kCache = kN * kAC;        // 16,384,000
constexpr int kRows  = kB * kA;         // 8192 (b,a) rows of 512 floats

constexpr int kCacheSplit = 2;                  // blocks per class row
constexpr int kCacheBlks  = kN * kCacheSplit;   // 2000
constexpr int kF4PerClass = kAC / 4;            // 4096 float4
constexpr int kF4PerHalf  = kF4PerClass / kCacheSplit;  // 2048
constexpr int kAccN       = kF4PerHalf / 256;   // 8 float4 per thread

constexpr int kExRowsPerBlk = 8;                // rows per exchange block
constexpr int kExBlks = kRows / kExRowsPerBlk;  // 1024
constexpr int kExIters = kExRowsPerBlk * 128 / 256;  // 4 float4 per thread

// ---------------------------------------------------------------------------
// Kernel 1: per-sample wave: cls[b] = argmax_n labels[b,n] (first-max), then
// lanes 0..31 compute the per-(b,a)-row source descriptor:
//   srcrow[row] = (rand_u[row] > 0.5) ? 0x80000000 | (cls*32 + a) : row
// ---------------------------------------------------------------------------
__global__ __launch_bounds__(256) void k_prep(
    const float* __restrict__ labels,
    const float* __restrict__ rand_u,
    int* __restrict__ cls,
    int* __restrict__ srcrow)
{
    const int wave = threadIdx.x >> 6;
    const int lane = threadIdx.x & 63;
    const int b = blockIdx.x * 4 + wave;
    const float* row = labels + (size_t)b * kN;
    float best = -3.4e38f;
    int   bidx = kN;
    for (int n = lane; n < kN; n += 64) {
        float v = row[n];                      // coalesced across lanes
        if (v > best) { best = v; bidx = n; }  // ascending n => first max kept
    }
    #pragma unroll
    for (int off = 32; off >= 1; off >>= 1) {  // butterfly: all lanes converge
        float ov = __shfl_xor(best, off, 64);
        int   oi = __shfl_xor(bidx, off, 64);
        if (ov > best || (ov == best && oi < bidx)) { best = ov; bidx = oi; }
    }
    if (lane == 0) cls[b] = bidx;
    if (lane < kA) {
        const int r = b * kA + lane;
        const float ru = rand_u[r];
        srcrow[r] = (ru > 0.5f) ? (int)(0x80000000u | (unsigned)(bidx * kA + lane))
                                : r;
    }
}

// ---------------------------------------------------------------------------
// Kernel 2 (fused):
//  blocks [0, 2000):  new_cache (class n = blk/2, half = blk&1) + new_count
//    ballot+barrier FIRST (barrier drains only the 4B cls load), then
//    unimpeded 8-deep load->(add)->store pipelines; pure-copy fast path for
//    the 97% of blocks with zero matches.
//  blocks [2000, 3024): exch_features — batched 3-stage copy (4 srcrow loads,
//    4 vec loads, 4 stores — each stage fully in flight).
// ---------------------------------------------------------------------------
__global__ __launch_bounds__(256) void k_main(
    const float* __restrict__ features,
    const float* __restrict__ anchor,
    const float* __restrict__ cache,
    const float* __restrict__ count,
    const int*   __restrict__ cls,
    const int*   __restrict__ srcrow,
    float* __restrict__ out_feat,
    float* __restrict__ out_cache,
    float* __restrict__ out_count)
{
    const int blk = blockIdx.x;
    const int t = threadIdx.x;
    if (blk < kCacheBlks) {
        // -------- cache accumulate: 2 blocks per class, ballot match list ----
        const int n    = blk >> 1;
        const int half = blk & 1;

        __shared__ unsigned long long masks[4];
        const int myc = cls[t];                          // coalesced 1KB read
        unsigned long long mb = __ballot(myc == n);
        if ((t & 63) == 0) masks[t >> 6] = mb;
        __syncthreads();                                 // drains only cls load

        unsigned long long m[4];
        int mtot = 0;
        #pragma unroll
        for (int w = 0; w < 4; ++w) { m[w] = masks[w]; mtot += __popcll(m[w]); }

        const size_t base = (size_t)n * kF4PerClass + (size_t)half * kF4PerHalf;
        const f32x4* src = (const f32x4*)cache + base;
        f32x4*       dst = (f32x4*)out_cache + base;

        if (mtot == 0) {
            // pure copy — 8 independent load->store chains, no barrier after
            #pragma unroll
            for (int i = 0; i < kAccN; ++i) {
                f32x4 v = src[t + i * 256];
                __builtin_nontemporal_store(v, &dst[t + i * 256]);
            }
        } else {
            f32x4 acc[kAccN];
            #pragma unroll
            for (int i = 0; i < kAccN; ++i) acc[i] = src[t + i * 256];
            #pragma unroll
            for (int w = 0; w < 4; ++w) {
                unsigned long long mm = m[w];
                while (mm) {
                    const int bit = __ffsll((long long)mm) - 1;
                    mm &= mm - 1;
                    const int b = w * 64 + bit;          // ascending b order
                    const f32x4* f = (const f32x4*)features
                                    + (size_t)b * kF4PerClass + (size_t)half * kF4PerHalf;
                    #pragma unroll
                    for (int i = 0; i < kAccN; ++i)
                        acc[i] += f[t + i * 256];
                }
            }
            #pragma unroll
            for (int i = 0; i < kAccN; ++i)
                __builtin_nontemporal_store(acc[i], &dst[t + i * 256]);
        }

        if (t == 0 && half == 0) out_count[n] = count[n] + (float)mtot;
    } else {
        // -------- exchange: 8 rows/block, 3-stage batched copy --------
        const int rblk = blk - kCacheBlks;               // 0..1023
        const int j0   = rblk * (kExRowsPerBlk * 128);   // base float4 index
        const f32x4* features4 = (const f32x4*)features;
        const f32x4* anchor4   = (const f32x4*)anchor;
        f32x4*       out4      = (f32x4*)out_feat;

        int s[kExIters];
        #pragma unroll
        for (int k = 0; k < kExIters; ++k)               // 4 srcrow loads in flight
            s[k] = srcrow[(j0 + k * 256 + t) >> 7];

        f32x4 v[kExIters];
        #pragma unroll
        for (int k = 0; k < kExIters; ++k) {             // 4 vec loads in flight
            const int c4 = (j0 + k * 256 + t) & 127;
            const f32x4* srcb = (s[k] >= 0) ? features4 : anchor4;
            v[k] = srcb[(size_t)(s[k] & 0x7fffffff) * 128 + c4];
        }
        #pragma unroll
        for (int k = 0; k < kExIters; ++k)
            __builtin_nontemporal_store(v[k], &out4[j0 + k * 256 + t]);
    }
}

// ---------------------------------------------------------------------------
extern "C" void kernel_launch(void* const* d_in, const int* in_sizes, int n_in,
                              void* d_out, int out_size, void* d_ws, size_t ws_size,
                              hipStream_t stream) {
    const float* features = (const float*)d_in[0];   // (B,A,C)
    const float* labels   = (const float*)d_in[1];   // (B,N)
    const float* anchor   = (const float*)d_in[2];   // (N,A,C)
    const float* cache    = (const float*)d_in[3];   // (N,A,C)
    const float* count    = (const float*)d_in[4];   // (N,)
    const float* rand_u   = (const float*)d_in[5];   // (B,A)

    float* out_feat  = (float*)d_out;                // (B,A,C)
    float* out_cache = out_feat + kFeat;             // (N,A,C)
    float* out_count = out_cache + kCache;           // (N,)

    int* cls    = (int*)d_ws;                        // 256 ints
    int* srcrow = cls + kB;                          // 8192 ints

    k_prep<<<kB / 4, 256, 0, stream>>>(labels, rand_u, cls, srcrow);
    k_main<<<kCacheBlks + kExBlks, 256, 0, stream>>>(features, anchor, cache, count,
                                                     cls, srcrow,
                                                     out_feat, out_cache, out_count);
}